// Round 5
// baseline (428.894 us; speedup 1.0000x reference)
//
#include <hip/hip_runtime.h>
#include <hip/hip_bf16.h>
#include <cstdint>
#include <cstddef>

#define BB 2
#define SS 2048
#define DD 2048
#define HH 16
#define HDIM 128
// 1/sqrt(128) * log2(e): folded into Q so softmax uses exp2 directly
#define QSCALE 0.12751743f

typedef short bf16x8 __attribute__((ext_vector_type(8)));
typedef float f32x4 __attribute__((ext_vector_type(4)));
typedef float f32x16 __attribute__((ext_vector_type(16)));

__device__ __forceinline__ ushort f2bf(float f) {
    union { float f; uint32_t u; } v; v.f = f;
    uint32_t u = v.u;
    u += 0x7fffu + ((u >> 16) & 1u);
    return (ushort)(u >> 16);
}

// cheap round-half-up f32->bf16 (2 VALU ops); fine for nonnegative p
__device__ __forceinline__ ushort f2bf_fast(float f) {
    union { float f; uint32_t u; } v; v.f = f;
    return (ushort)((v.u + 0x8000u) >> 16);
}

// async 16B global -> LDS (wave-uniform LDS base + lane*16)
__device__ __forceinline__ void gl16(const ushort* g, ushort* l) {
    __builtin_amdgcn_global_load_lds(
        (const __attribute__((address_space(1))) unsigned int*)g,
        (__attribute__((address_space(3))) unsigned int*)l,
        16, 0, 0);
}

// ---------------------------------------------------------------------------
// Prep kernels
// ---------------------------------------------------------------------------
__global__ __launch_bounds__(256) void cast_x_kernel(
    const float* __restrict__ X, ushort* __restrict__ Xb)
{
    size_t idx = ((size_t)blockIdx.x * 256 + threadIdx.x) * 8;
    float4 a = *(const float4*)(X + idx);
    float4 b = *(const float4*)(X + idx + 4);
    ushort4 o0, o1;
    o0.x = f2bf(a.x); o0.y = f2bf(a.y); o0.z = f2bf(a.z); o0.w = f2bf(a.w);
    o1.x = f2bf(b.x); o1.y = f2bf(b.y); o1.z = f2bf(b.z); o1.w = f2bf(b.w);
    *(ushort4*)(Xb + idx) = o0;
    *(ushort4*)(Xb + idx + 4) = o1;
}

// W fp32 [K][N] row-major -> Wt bf16 [N][K]
__global__ __launch_bounds__(256) void transpose_cast_kernel(
    const float* __restrict__ W, ushort* __restrict__ Wt, int K, int N)
{
    __shared__ ushort tile[32][36];
    const int n0 = blockIdx.x * 32;
    const int k0 = blockIdx.y * 32;
    const int t = threadIdx.x;
    const int r = t >> 3;
    const int c = (t & 7) * 4;
    float4 a = *(const float4*)(W + (size_t)(k0 + r) * N + n0 + c);
    tile[r][c + 0] = f2bf(a.x); tile[r][c + 1] = f2bf(a.y);
    tile[r][c + 2] = f2bf(a.z); tile[r][c + 3] = f2bf(a.w);
    __syncthreads();
    ushort4 o;
    o.x = tile[c + 0][r]; o.y = tile[c + 1][r];
    o.z = tile[c + 2][r]; o.w = tile[c + 3][r];
    *(ushort4*)(Wt + (size_t)(n0 + r) * K + k0 + c) = o;
}

// V bf16 [BH][S][HD] -> Vt bf16 [BH][HD][S]
__global__ __launch_bounds__(256) void transpose_v_kernel(
    const ushort* __restrict__ V, ushort* __restrict__ Vt)
{
    __shared__ ushort tile[32][36];
    const int s0 = blockIdx.x * 32;
    const int h0 = blockIdx.y * 32;
    const int bh = blockIdx.z;
    const ushort* Vp = V + (size_t)bh * SS * HDIM;
    ushort* Vtp = Vt + (size_t)bh * HDIM * SS;
    const int t = threadIdx.x;
    const int r = t >> 3;
    const int c = (t & 7) * 4;
    *(ushort4*)&tile[r][c] = *(const ushort4*)(Vp + (size_t)(s0 + r) * HDIM + h0 + c);
    __syncthreads();
    ushort4 o;
    o.x = tile[c + 0][r]; o.y = tile[c + 1][r];
    o.z = tile[c + 2][r]; o.w = tile[c + 3][r];
    *(ushort4*)(Vtp + (size_t)(h0 + r) * SS + s0 + c) = o;
}

// ---------------------------------------------------------------------------
// MFMA GEMM: C[M,N] = A[M,K] @ Bt[N,K]^T, 128x128 tile, BK=32, m97 staging.
// Inner compute: 32x32x16 MFMA, each wave 2x2 tiles of 32x32.
// A/B frag: row = lane&31, k = (lane>>5)*8 + j (validated by attn kernel).
// C layout: col = lane&31, row = (r&3) + 8*(r>>2) + 4*(lane>>5).
// ---------------------------------------------------------------------------
__global__ __launch_bounds__(256) void gemm_qkv_kernel(
    const ushort* __restrict__ A, const ushort* __restrict__ Bt,
    const float* __restrict__ bias,
    ushort* __restrict__ Qo, ushort* __restrict__ Ko, ushort* __restrict__ Vo)
{
    const int n0 = blockIdx.x * 128;
    const int m0 = blockIdx.y * 128;
    __shared__ ushort As[128 * 32];
    __shared__ ushort Bs[128 * 32];
    const int t = threadIdx.x, w = t >> 6, lane = t & 63;
    const int l31 = lane & 31, hh = lane >> 5;
    const int lrow = lane >> 2, lks = lane & 3;
    const int wr = w >> 1, wc = w & 1;

    f32x16 acc[2][2];
#pragma unroll
    for (int i = 0; i < 2; ++i)
#pragma unroll
        for (int j = 0; j < 2; ++j) acc[i][j] = (f32x16)0.f;

    for (int k0 = 0; k0 < DD; k0 += 32) {
        __syncthreads();
#pragma unroll
        for (int q = 0; q < 2; ++q) {
            int e = w * 2 + q;
            int row = e * 16 + lrow;
            gl16(A  + (size_t)(m0 + row) * DD + k0 + lks * 8, &As[e * 512]);
            gl16(Bt + (size_t)(n0 + row) * DD + k0 + lks * 8, &Bs[e * 512]);
        }
        __syncthreads();
#pragma unroll
        for (int k16 = 0; k16 < 2; ++k16) {
            bf16x8 ar0 = *(const bf16x8*)&As[(wr * 64 + l31) * 32 + k16 * 16 + hh * 8];
            bf16x8 ar1 = *(const bf16x8*)&As[(wr * 64 + 32 + l31) * 32 + k16 * 16 + hh * 8];
            bf16x8 br0 = *(const bf16x8*)&Bs[(wc * 64 + l31) * 32 + k16 * 16 + hh * 8];
            bf16x8 br1 = *(const bf16x8*)&Bs[(wc * 64 + 32 + l31) * 32 + k16 * 16 + hh * 8];
            acc[0][0] = __builtin_amdgcn_mfma_f32_32x32x16_bf16(ar0, br0, acc[0][0], 0, 0, 0);
            acc[0][1] = __builtin_amdgcn_mfma_f32_32x32x16_bf16(ar0, br1, acc[0][1], 0, 0, 0);
            acc[1][0] = __builtin_amdgcn_mfma_f32_32x32x16_bf16(ar1, br0, acc[1][0], 0, 0, 0);
            acc[1][1] = __builtin_amdgcn_mfma_f32_32x32x16_bf16(ar1, br1, acc[1][1], 0, 0, 0);
        }
    }

    // Epilogue: bias, fold QSCALE into Q, scatter bf16 into [B,H,S,HD]
    const int bidx = m0 >> 11;
    const int which = n0 >> 11;           // block-uniform (n0 % 128 == 0)
    ushort* dst = (which == 0) ? Qo : ((which == 1) ? Ko : Vo);
    const float sc = (which == 0) ? QSCALE : 1.0f;
#pragma unroll
    for (int j = 0; j < 2; ++j) {
        int n = n0 + wc * 64 + j * 32 + l31;
        int c = n & 2047, h = c >> 7, hd = c & 127;
        float bv = bias[n];
        size_t base = ((size_t)(bidx * HH + h) * SS) * HDIM + hd;
#pragma unroll
        for (int i = 0; i < 2; ++i) {
#pragma unroll
            for (int r = 0; r < 16; ++r) {
                int s = (m0 & 2047) + wr * 64 + i * 32 + (r & 3) + 8 * (r >> 2) + 4 * hh;
                dst[base + (size_t)s * HDIM] = f2bf((acc[i][j][r] + bv) * sc);
            }
        }
    }
}

__global__ __launch_bounds__(256) void gemm_out_kernel(
    const ushort* __restrict__ A, const ushort* __restrict__ Bt,
    const float* __restrict__ bias, float* __restrict__ Out)
{
    const int n0 = blockIdx.x * 128;
    const int m0 = blockIdx.y * 128;
    __shared__ ushort As[128 * 32];
    __shared__ ushort Bs[128 * 32];
    const int t = threadIdx.x, w = t >> 6, lane = t & 63;
    const int l31 = lane & 31, hh = lane >> 5;
    const int lrow = lane >> 2, lks = lane & 3;
    const int wr = w >> 1, wc = w & 1;

    f32x16 acc[2][2];
#pragma unroll
    for (int i = 0; i < 2; ++i)
#pragma unroll
        for (int j = 0; j < 2; ++j) acc[i][j] = (f32x16)0.f;

    for (int k0 = 0; k0 < DD; k0 += 32) {
        __syncthreads();
#pragma unroll
        for (int q = 0; q < 2; ++q) {
            int e = w * 2 + q;
            int row = e * 16 + lrow;
            gl16(A  + (size_t)(m0 + row) * DD + k0 + lks * 8, &As[e * 512]);
            gl16(Bt + (size_t)(n0 + row) * DD + k0 + lks * 8, &Bs[e * 512]);
        }
        __syncthreads();
#pragma unroll
        for (int k16 = 0; k16 < 2; ++k16) {
            bf16x8 ar0 = *(const bf16x8*)&As[(wr * 64 + l31) * 32 + k16 * 16 + hh * 8];
            bf16x8 ar1 = *(const bf16x8*)&As[(wr * 64 + 32 + l31) * 32 + k16 * 16 + hh * 8];
            bf16x8 br0 = *(const bf16x8*)&Bs[(wc * 64 + l31) * 32 + k16 * 16 + hh * 8];
            bf16x8 br1 = *(const bf16x8*)&Bs[(wc * 64 + 32 + l31) * 32 + k16 * 16 + hh * 8];
            acc[0][0] = __builtin_amdgcn_mfma_f32_32x32x16_bf16(ar0, br0, acc[0][0], 0, 0, 0);
            acc[0][1] = __builtin_amdgcn_mfma_f32_32x32x16_bf16(ar0, br1, acc[0][1], 0, 0, 0);
            acc[1][0] = __builtin_amdgcn_mfma_f32_32x32x16_bf16(ar1, br0, acc[1][0], 0, 0, 0);
            acc[1][1] = __builtin_amdgcn_mfma_f32_32x32x16_bf16(ar1, br1, acc[1][1], 0, 0, 0);
        }
    }

#pragma unroll
    for (int j = 0; j < 2; ++j) {
        int n = n0 + wc * 64 + j * 32 + l31;
        float bv = bias[n];
#pragma unroll
        for (int i = 0; i < 2; ++i) {
#pragma unroll
            for (int r = 0; r < 16; ++r) {
                int m = m0 + wr * 64 + i * 32 + (r & 3) + 8 * (r >> 2) + 4 * hh;
                Out[(size_t)m * DD + n] = acc[i][j][r] + bv;
            }
        }
    }
}

// ---------------------------------------------------------------------------
// MFMA flash attention (round-4 design, unchanged): 32x32x16 MFMA,
// 128 q-rows/block, 4 waves; wave w owns q-rows q0+w*32..+31.
// XOR chunk swizzles applied via the GLOBAL address in global_load_lds.
// Softmax: fixed reference M=0; l via P*ones MFMA.
// LDS: Ks 16K + Vs 16K + Ps 8K = 40 KB.
// ---------------------------------------------------------------------------
__global__ __launch_bounds__(256, 2) void attn_mfma_kernel(
    const ushort* __restrict__ Q, const ushort* __restrict__ K,
    const ushort* __restrict__ Vt, ushort* __restrict__ Y)
{
    const int bh = blockIdx.y;
    const int qt = gridDim.x - 1 - blockIdx.x;   // heavy tiles first
    const int q0 = qt * 128;
    const int b = bh >> 4, h = bh & 15;

    __shared__ ushort Ks[4 * 64 * 32];   // panel ks: dims ks*32..+32, 64 keys
    __shared__ ushort Vs[2 * 128 * 32];  // panel kp: keys kp*32..+32, 128 dims
    __shared__ ushort Ps[128 * 32];      // one 32-key half, 128 q-rows

    const int t = threadIdx.x, w = t >> 6, lane = t & 63;
    const int l31 = lane & 31, hh = lane >> 5;
    const int lrow = lane >> 2, lks = lane & 3;
    const int sw31 = l31 & 3;            // read-side swizzle key

    const ushort* Qp = Q  + (size_t)bh * SS * HDIM;
    const ushort* Kp = K  + (size_t)bh * SS * HDIM;
    const ushort* Vp = Vt + (size_t)bh * HDIM * SS;

    // Q fragments to registers: A[m=l31][k=kb2*16+hh*8+j]
    bf16x8 aq[8];
#pragma unroll
    for (int kb2 = 0; kb2 < 8; ++kb2)
        aq[kb2] = *(const bf16x8*)(Qp + (size_t)(q0 + w * 32 + l31) * HDIM + kb2 * 16 + hh * 8);

    bf16x8 ones;
#pragma unroll
    for (int j = 0; j < 8; ++j) ones[j] = (short)0x3F80;  // bf16 1.0

    f32x16 O[4];
#pragma unroll
    for (int nt = 0; nt < 4; ++nt) O[nt] = (f32x16)0.f;
    f32x16 Ol = (f32x16)0.f;

    const int kbdiag = 2 * qt + (w >> 1);
    const int nkb = 2 * qt + 2;

    for (int kb = 0; kb < nkb; ++kb) {
        const int kbase = kb * 64;
        __syncthreads();   // prior iteration's Ks/Vs reads complete
        // stage Ks panel w (dims w*32..+32, 64 keys), chunk-swizzled by key
#pragma unroll
        for (int g = 0; g < 4; ++g) {
            int key = g * 16 + lrow;
            int chunk = lks ^ (key & 3);
            gl16(Kp + (size_t)(kbase + key) * HDIM + w * 32 + chunk * 8,
                 &Ks[w * 2048 + g * 512]);
        }
        // stage Vs dims w*32..+32 for both key-panels, chunk-swizzled by dim
#pragma unroll
        for (int g = 0; g < 4; ++g) {
            int pan = g >> 1, sub = g & 1;
            int dim = w * 32 + sub * 16 + lrow;
            int chunk = lks ^ (dim & 3);
            gl16(Vp + (size_t)dim * SS + kbase + pan * 32 + chunk * 8,
                 &Vs[pan * 4096 + (w * 32 + sub * 16) * 32]);
        }
        __syncthreads();   // staged data visible

        const bool active = (kb <= kbdiag);
        if (active) {
            // S = Q K^T, two 32-key n-tiles
            f32x16 sc0 = (f32x16)0.f, sc1 = (f32x16)0.f;
#pragma unroll
            for (int kb2 = 0; kb2 < 8; ++kb2) {
                int c = (kb2 & 1) * 2 + hh;
                int co = ((c ^ sw31) * 8);
                bf16x8 bk0 = *(const bf16x8*)&Ks[(kb2 >> 1) * 2048 + l31 * 32 + co];
                bf16x8 bk1 = *(const bf16x8*)&Ks[(kb2 >> 1) * 2048 + (32 + l31) * 32 + co];
                sc0 = __builtin_amdgcn_mfma_f32_32x32x16_bf16(aq[kb2], bk0, sc0, 0, 0, 0);
                sc1 = __builtin_amdgcn_mfma_f32_32x32x16_bf16(aq[kb2], bk1, sc1, 0, 0, 0);
            }

            if (kb == kbdiag) {   // diagonal: causal mask
#pragma unroll
                for (int r = 0; r < 16; ++r) {
                    int rowg = q0 + w * 32 + (r & 3) + 8 * (r >> 2) + 4 * hh;
                    if (kbase + l31 > rowg)      sc0[r] = -1e30f;
                    if (kbase + 32 + l31 > rowg) sc1[r] = -1e30f;
                }
            }

            // per 32-key half: exp2 -> Ps (swizzled) -> PV MFMA
#pragma unroll
            for (int half = 0; half < 2; ++half) {
#pragma unroll
                for (int r = 0; r < 16; ++r) {
                    float sv = (half == 0) ? sc0[r] : sc1[r];
                    float p = __builtin_amdgcn_exp2f(sv);
                    int row = w * 32 + (r & 3) + 8 * (r >> 2) + 4 * hh;
                    Ps[row * 32 + (((l31 >> 3) ^ (r & 3)) << 3) + (l31 & 7)] = f2bf_fast(p);
                }
#pragma unroll
                for (int kblk2 = 0; kblk2 < 2; ++kblk2) {
                    int c = kblk2 * 2 + hh;
                    int co = ((c ^ sw31) * 8);
                    bf16x8 ap = *(const bf16x8*)&Ps[(w * 32 + l31) * 32 + co];
#pragma unroll
                    for (int nt = 0; nt < 4; ++nt) {
                        bf16x8 bv = *(const bf16x8*)&Vs[half * 4096 + (nt * 32 + l31) * 32 + co];
                        O[nt] = __builtin_amdgcn_mfma_f32_32x32x16_bf16(ap, bv, O[nt], 0, 0, 0);
                    }
                    Ol = __builtin_amdgcn_mfma_f32_32x32x16_bf16(ap, ones, Ol, 0, 0, 0);
                }
            }
        }
    }

    // epilogue: divide by l, write Y[b,s,h*128+hd]
#pragma unroll
    for (int r = 0; r < 16; ++r) {
        int s = q0 + w * 32 + (r & 3) + 8 * (r >> 2) + 4 * hh;
        float inv = 1.0f / Ol[r];
        size_t base = ((size_t)(b * SS + s)) * DD + h * HDIM;
#pragma unroll
        for (int nt = 0; nt < 4; ++nt)
            Y[base + nt * 32 + l31] = f2bf(O[nt][r] * inv);
    }
}

// ---------------------------------------------------------------------------
extern "C" void kernel_launch(void* const* d_in, const int* in_sizes, int n_in,
                              void* d_out, int out_size, void* d_ws, size_t ws_size,
                              hipStream_t stream) {
    const float* x     = (const float*)d_in[0];
    const float* w_qkv = (const float*)d_in[1];
    const float* b_qkv = (const float*)d_in[2];
    const float* w_out = (const float*)d_in[3];
    const float* b_out = (const float*)d_in[4];
    float* out = (float*)d_out;

    ushort* ws  = (ushort*)d_ws;
    ushort* xb  = ws;                      // 8,388,608
    ushort* wtq = xb + 8388608;            // 12,582,912
    ushort* wto = wtq + 12582912;          // 4,194,304
    ushort* q   = wto + 4194304;           // 8,388,608
    ushort* k   = q + 8388608;
    ushort* v   = k + 8388608;             // [B,H,S,HD]
    ushort* vt  = v + 8388608;             // [B,H,HD,S]
    ushort* y   = vt + 8388608;

    cast_x_kernel<<<4096, 256, 0, stream>>>(x, xb);
    transpose_cast_kernel<<<dim3(192, 64), 256, 0, stream>>>(w_qkv, wtq, DD, 3 * DD);
    transpose_cast_kernel<<<dim3(64, 64), 256, 0, stream>>>(w_out, wto, DD, DD);
    gemm_qkv_kernel<<<dim3(48, 32), 256, 0, stream>>>(xb, wtq, b_qkv, q, k, v);
    transpose_v_kernel<<<dim3(64, 4, 32), 256, 0, stream>>>(v, vt);
    attn_mfma_kernel<<<dim3(16, 32), 256, 0, stream>>>(q, k, vt, y);
    gemm_out_kernel<<<dim3(16, 32), 256, 0, stream>>>(y, wto, b_out, out);
}

// Round 6
// 408.407 us; speedup vs baseline: 1.0502x; 1.0502x over previous
//
#include <hip/hip_runtime.h>
#include <hip/hip_bf16.h>
#include <cstdint>
#include <cstddef>

#define BB 2
#define SS 2048
#define DD 2048
#define HH 16
#define HDIM 128
// 1/sqrt(128) * log2(e): folded into Q so softmax uses exp2 directly
#define QSCALE 0.12751743f

typedef short bf16x8 __attribute__((ext_vector_type(8)));
typedef float f32x4 __attribute__((ext_vector_type(4)));
typedef float f32x16 __attribute__((ext_vector_type(16)));

__device__ __forceinline__ ushort f2bf(float f) {
    union { float f; uint32_t u; } v; v.f = f;
    uint32_t u = v.u;
    u += 0x7fffu + ((u >> 16) & 1u);
    return (ushort)(u >> 16);
}

// cheap round-half-up f32->bf16 (2 VALU ops); fine for nonnegative p
__device__ __forceinline__ ushort f2bf_fast(float f) {
    union { float f; uint32_t u; } v; v.f = f;
    return (ushort)((v.u + 0x8000u) >> 16);
}

// async 16B global -> LDS (wave-uniform LDS base + lane*16)
__device__ __forceinline__ void gl16(const ushort* g, ushort* l) {
    __builtin_amdgcn_global_load_lds(
        (const __attribute__((address_space(1))) unsigned int*)g,
        (__attribute__((address_space(3))) unsigned int*)l,
        16, 0, 0);
}

// LDS rows are 64 B (32 ushorts) = 4 chunks of 16 B. Chunk c of row r is
// stored at physical chunk c ^ ((r>>1)&3). Combined with the 16-bank row
// parity offset this spreads a 32-lane b128 column-read over all 8 16B
// spans (4 lanes each) -> bank-conflict-free (8-cycle floor).

// ---------------------------------------------------------------------------
// Prep kernels
// ---------------------------------------------------------------------------
__global__ __launch_bounds__(256) void cast_x_kernel(
    const float* __restrict__ X, ushort* __restrict__ Xb)
{
    size_t idx = ((size_t)blockIdx.x * 256 + threadIdx.x) * 8;
    float4 a = *(const float4*)(X + idx);
    float4 b = *(const float4*)(X + idx + 4);
    ushort4 o0, o1;
    o0.x = f2bf(a.x); o0.y = f2bf(a.y); o0.z = f2bf(a.z); o0.w = f2bf(a.w);
    o1.x = f2bf(b.x); o1.y = f2bf(b.y); o1.z = f2bf(b.z); o1.w = f2bf(b.w);
    *(ushort4*)(Xb + idx) = o0;
    *(ushort4*)(Xb + idx + 4) = o1;
}

// W fp32 [K][N] row-major -> Wt bf16 [N][K]
__global__ __launch_bounds__(256) void transpose_cast_kernel(
    const float* __restrict__ W, ushort* __restrict__ Wt, int K, int N)
{
    __shared__ ushort tile[32][36];
    const int n0 = blockIdx.x * 32;
    const int k0 = blockIdx.y * 32;
    const int t = threadIdx.x;
    const int r = t >> 3;
    const int c = (t & 7) * 4;
    float4 a = *(const float4*)(W + (size_t)(k0 + r) * N + n0 + c);
    tile[r][c + 0] = f2bf(a.x); tile[r][c + 1] = f2bf(a.y);
    tile[r][c + 2] = f2bf(a.z); tile[r][c + 3] = f2bf(a.w);
    __syncthreads();
    ushort4 o;
    o.x = tile[c + 0][r]; o.y = tile[c + 1][r];
    o.z = tile[c + 2][r]; o.w = tile[c + 3][r];
    *(ushort4*)(Wt + (size_t)(n0 + r) * K + k0 + c) = o;
}

// V bf16 [BH][S][HD] -> Vt bf16 [BH][HD][S]
__global__ __launch_bounds__(256) void transpose_v_kernel(
    const ushort* __restrict__ V, ushort* __restrict__ Vt)
{
    __shared__ ushort tile[32][36];
    const int s0 = blockIdx.x * 32;
    const int h0 = blockIdx.y * 32;
    const int bh = blockIdx.z;
    const ushort* Vp = V + (size_t)bh * SS * HDIM;
    ushort* Vtp = Vt + (size_t)bh * HDIM * SS;
    const int t = threadIdx.x;
    const int r = t >> 3;
    const int c = (t & 7) * 4;
    *(ushort4*)&tile[r][c] = *(const ushort4*)(Vp + (size_t)(s0 + r) * HDIM + h0 + c);
    __syncthreads();
    ushort4 o;
    o.x = tile[c + 0][r]; o.y = tile[c + 1][r];
    o.z = tile[c + 2][r]; o.w = tile[c + 3][r];
    *(ushort4*)(Vtp + (size_t)(h0 + r) * SS + s0 + c) = o;
}

// ---------------------------------------------------------------------------
// MFMA GEMM: C[M,N] = A[M,K] @ Bt[N,K]^T, 128x128 tile, BK=32, m97 staging.
// Inner: 32x32x16 MFMA, each wave 2x2 tiles of 32x32. Swizzled LDS chunks.
// ---------------------------------------------------------------------------
__global__ __launch_bounds__(256) void gemm_qkv_kernel(
    const ushort* __restrict__ A, const ushort* __restrict__ Bt,
    const float* __restrict__ bias,
    ushort* __restrict__ Qo, ushort* __restrict__ Ko, ushort* __restrict__ Vo)
{
    const int n0 = blockIdx.x * 128;
    const int m0 = blockIdx.y * 128;
    __shared__ ushort As[128 * 32];
    __shared__ ushort Bs[128 * 32];
    const int t = threadIdx.x, w = t >> 6, lane = t & 63;
    const int l31 = lane & 31, hh = lane >> 5;
    const int lrow = lane >> 2, lks = lane & 3;
    const int wr = w >> 1, wc = w & 1;
    const int swst = (lrow >> 1) & 3;     // store-side swizzle key
    const int swr  = (l31 >> 1) & 3;      // read-side swizzle key

    f32x16 acc[2][2];
#pragma unroll
    for (int i = 0; i < 2; ++i)
#pragma unroll
        for (int j = 0; j < 2; ++j) acc[i][j] = (f32x16)0.f;

    for (int k0 = 0; k0 < DD; k0 += 32) {
        __syncthreads();
#pragma unroll
        for (int q = 0; q < 2; ++q) {
            int e = w * 2 + q;
            int row = e * 16 + lrow;
            gl16(A  + (size_t)(m0 + row) * DD + k0 + (lks ^ swst) * 8, &As[e * 512]);
            gl16(Bt + (size_t)(n0 + row) * DD + k0 + (lks ^ swst) * 8, &Bs[e * 512]);
        }
        __syncthreads();
#pragma unroll
        for (int k16 = 0; k16 < 2; ++k16) {
            int co = ((k16 * 2 + hh) ^ swr) * 8;
            bf16x8 ar0 = *(const bf16x8*)&As[(wr * 64 + l31) * 32 + co];
            bf16x8 ar1 = *(const bf16x8*)&As[(wr * 64 + 32 + l31) * 32 + co];
            bf16x8 br0 = *(const bf16x8*)&Bs[(wc * 64 + l31) * 32 + co];
            bf16x8 br1 = *(const bf16x8*)&Bs[(wc * 64 + 32 + l31) * 32 + co];
            acc[0][0] = __builtin_amdgcn_mfma_f32_32x32x16_bf16(ar0, br0, acc[0][0], 0, 0, 0);
            acc[0][1] = __builtin_amdgcn_mfma_f32_32x32x16_bf16(ar0, br1, acc[0][1], 0, 0, 0);
            acc[1][0] = __builtin_amdgcn_mfma_f32_32x32x16_bf16(ar1, br0, acc[1][0], 0, 0, 0);
            acc[1][1] = __builtin_amdgcn_mfma_f32_32x32x16_bf16(ar1, br1, acc[1][1], 0, 0, 0);
        }
    }

    // Epilogue: bias, fold QSCALE into Q, scatter bf16 into [B,H,S,HD]
    const int bidx = m0 >> 11;
    const int which = n0 >> 11;           // block-uniform (n0 % 128 == 0)
    ushort* dst = (which == 0) ? Qo : ((which == 1) ? Ko : Vo);
    const float sc = (which == 0) ? QSCALE : 1.0f;
#pragma unroll
    for (int j = 0; j < 2; ++j) {
        int n = n0 + wc * 64 + j * 32 + l31;
        int c = n & 2047, h = c >> 7, hd = c & 127;
        float bv = bias[n];
        size_t base = ((size_t)(bidx * HH + h) * SS) * HDIM + hd;
#pragma unroll
        for (int i = 0; i < 2; ++i) {
#pragma unroll
            for (int r = 0; r < 16; ++r) {
                int s = (m0 & 2047) + wr * 64 + i * 32 + (r & 3) + 8 * (r >> 2) + 4 * hh;
                dst[base + (size_t)s * HDIM] = f2bf((acc[i][j][r] + bv) * sc);
            }
        }
    }
}

__global__ __launch_bounds__(256) void gemm_out_kernel(
    const ushort* __restrict__ A, const ushort* __restrict__ Bt,
    const float* __restrict__ bias, float* __restrict__ Out)
{
    const int n0 = blockIdx.x * 128;
    const int m0 = blockIdx.y * 128;
    __shared__ ushort As[128 * 32];
    __shared__ ushort Bs[128 * 32];
    const int t = threadIdx.x, w = t >> 6, lane = t & 63;
    const int l31 = lane & 31, hh = lane >> 5;
    const int lrow = lane >> 2, lks = lane & 3;
    const int wr = w >> 1, wc = w & 1;
    const int swst = (lrow >> 1) & 3;
    const int swr  = (l31 >> 1) & 3;

    f32x16 acc[2][2];
#pragma unroll
    for (int i = 0; i < 2; ++i)
#pragma unroll
        for (int j = 0; j < 2; ++j) acc[i][j] = (f32x16)0.f;

    for (int k0 = 0; k0 < DD; k0 += 32) {
        __syncthreads();
#pragma unroll
        for (int q = 0; q < 2; ++q) {
            int e = w * 2 + q;
            int row = e * 16 + lrow;
            gl16(A  + (size_t)(m0 + row) * DD + k0 + (lks ^ swst) * 8, &As[e * 512]);
            gl16(Bt + (size_t)(n0 + row) * DD + k0 + (lks ^ swst) * 8, &Bs[e * 512]);
        }
        __syncthreads();
#pragma unroll
        for (int k16 = 0; k16 < 2; ++k16) {
            int co = ((k16 * 2 + hh) ^ swr) * 8;
            bf16x8 ar0 = *(const bf16x8*)&As[(wr * 64 + l31) * 32 + co];
            bf16x8 ar1 = *(const bf16x8*)&As[(wr * 64 + 32 + l31) * 32 + co];
            bf16x8 br0 = *(const bf16x8*)&Bs[(wc * 64 + l31) * 32 + co];
            bf16x8 br1 = *(const bf16x8*)&Bs[(wc * 64 + 32 + l31) * 32 + co];
            acc[0][0] = __builtin_amdgcn_mfma_f32_32x32x16_bf16(ar0, br0, acc[0][0], 0, 0, 0);
            acc[0][1] = __builtin_amdgcn_mfma_f32_32x32x16_bf16(ar0, br1, acc[0][1], 0, 0, 0);
            acc[1][0] = __builtin_amdgcn_mfma_f32_32x32x16_bf16(ar1, br0, acc[1][0], 0, 0, 0);
            acc[1][1] = __builtin_amdgcn_mfma_f32_32x32x16_bf16(ar1, br1, acc[1][1], 0, 0, 0);
        }
    }

#pragma unroll
    for (int j = 0; j < 2; ++j) {
        int n = n0 + wc * 64 + j * 32 + l31;
        float bv = bias[n];
#pragma unroll
        for (int i = 0; i < 2; ++i) {
#pragma unroll
            for (int r = 0; r < 16; ++r) {
                int m = m0 + wr * 64 + i * 32 + (r & 3) + 8 * (r >> 2) + 4 * hh;
                Out[(size_t)m * DD + n] = acc[i][j][r] + bv;
            }
        }
    }
}

// ---------------------------------------------------------------------------
// MFMA flash attention: 32x32x16 MFMA, 128 q-rows/block, 4 waves.
// Wave w owns q-rows q0+w*32..+31. Swizzled LDS chunks (conflict-free).
// Softmax: fixed reference M=0; l via P*ones MFMA.
// LDS: Ks 16K + Vs 16K + Ps 8K = 40 KB.
// ---------------------------------------------------------------------------
__global__ __launch_bounds__(256, 2) void attn_mfma_kernel(
    const ushort* __restrict__ Q, const ushort* __restrict__ K,
    const ushort* __restrict__ Vt, ushort* __restrict__ Y)
{
    const int bh = blockIdx.y;
    const int qt = gridDim.x - 1 - blockIdx.x;   // heavy tiles first
    const int q0 = qt * 128;
    const int b = bh >> 4, h = bh & 15;

    __shared__ ushort Ks[4 * 64 * 32];   // panel ks: dims ks*32..+32, 64 keys
    __shared__ ushort Vs[2 * 128 * 32];  // panel kp: keys kp*32..+32, 128 dims
    __shared__ ushort Ps[128 * 32];      // one 32-key half, 128 q-rows

    const int t = threadIdx.x, w = t >> 6, lane = t & 63;
    const int l31 = lane & 31, hh = lane >> 5;
    const int lrow = lane >> 2, lks = lane & 3;
    const int swst = (lrow >> 1) & 3;    // store-side swizzle key
    const int swr  = (l31 >> 1) & 3;     // read-side swizzle key

    const ushort* Qp = Q  + (size_t)bh * SS * HDIM;
    const ushort* Kp = K  + (size_t)bh * SS * HDIM;
    const ushort* Vp = Vt + (size_t)bh * HDIM * SS;

    // Q fragments to registers: A[m=l31][k=kb2*16+hh*8+j]
    bf16x8 aq[8];
#pragma unroll
    for (int kb2 = 0; kb2 < 8; ++kb2)
        aq[kb2] = *(const bf16x8*)(Qp + (size_t)(q0 + w * 32 + l31) * HDIM + kb2 * 16 + hh * 8);

    bf16x8 ones;
#pragma unroll
    for (int j = 0; j < 8; ++j) ones[j] = (short)0x3F80;  // bf16 1.0

    f32x16 O[4];
#pragma unroll
    for (int nt = 0; nt < 4; ++nt) O[nt] = (f32x16)0.f;
    f32x16 Ol = (f32x16)0.f;

    const int kbdiag = 2 * qt + (w >> 1);
    const int nkb = 2 * qt + 2;

    for (int kb = 0; kb < nkb; ++kb) {
        const int kbase = kb * 64;
        __syncthreads();   // prior iteration's Ks/Vs reads complete
        // stage Ks panel w (dims w*32..+32, 64 keys), swizzled chunks
#pragma unroll
        for (int g = 0; g < 4; ++g) {
            int key = g * 16 + lrow;
            gl16(Kp + (size_t)(kbase + key) * HDIM + w * 32 + (lks ^ swst) * 8,
                 &Ks[w * 2048 + g * 512]);
        }
        // stage Vs dims w*32..+32 for both key-panels, swizzled chunks
#pragma unroll
        for (int g = 0; g < 4; ++g) {
            int pan = g >> 1, sub = g & 1;
            int dim = w * 32 + sub * 16 + lrow;
            gl16(Vp + (size_t)dim * SS + kbase + pan * 32 + (lks ^ swst) * 8,
                 &Vs[pan * 4096 + (w * 32 + sub * 16) * 32]);
        }
        __syncthreads();   // staged data visible

        const bool active = (kb <= kbdiag);
        if (active) {
            // S = Q K^T, two 32-key n-tiles
            f32x16 sc0 = (f32x16)0.f, sc1 = (f32x16)0.f;
#pragma unroll
            for (int kb2 = 0; kb2 < 8; ++kb2) {
                int co = (((kb2 & 1) * 2 + hh) ^ swr) * 8;
                bf16x8 bk0 = *(const bf16x8*)&Ks[(kb2 >> 1) * 2048 + l31 * 32 + co];
                bf16x8 bk1 = *(const bf16x8*)&Ks[(kb2 >> 1) * 2048 + (32 + l31) * 32 + co];
                sc0 = __builtin_amdgcn_mfma_f32_32x32x16_bf16(aq[kb2], bk0, sc0, 0, 0, 0);
                sc1 = __builtin_amdgcn_mfma_f32_32x32x16_bf16(aq[kb2], bk1, sc1, 0, 0, 0);
            }

            if (kb == kbdiag) {   // diagonal: causal mask
#pragma unroll
                for (int r = 0; r < 16; ++r) {
                    int rowg = q0 + w * 32 + (r & 3) + 8 * (r >> 2) + 4 * hh;
                    if (kbase + l31 > rowg)      sc0[r] = -1e30f;
                    if (kbase + 32 + l31 > rowg) sc1[r] = -1e30f;
                }
            }

            // per 32-key half: exp2 -> Ps (swizzled) -> PV MFMA
#pragma unroll
            for (int half = 0; half < 2; ++half) {
#pragma unroll
                for (int r = 0; r < 16; ++r) {
                    float sv = (half == 0) ? sc0[r] : sc1[r];
                    float p = __builtin_amdgcn_exp2f(sv);
                    int rowm = (r & 3) + 8 * (r >> 2) + 4 * hh;
                    int pc = (l31 >> 3) ^ ((rowm >> 1) & 3);
                    Ps[(w * 32 + rowm) * 32 + (pc << 3) + (l31 & 7)] = f2bf_fast(p);
                }
#pragma unroll
                for (int kblk2 = 0; kblk2 < 2; ++kblk2) {
                    int co = ((kblk2 * 2 + hh) ^ swr) * 8;
                    bf16x8 ap = *(const bf16x8*)&Ps[(w * 32 + l31) * 32 + co];
#pragma unroll
                    for (int nt = 0; nt < 4; ++nt) {
                        bf16x8 bv = *(const bf16x8*)&Vs[half * 4096 + (nt * 32 + l31) * 32 + co];
                        O[nt] = __builtin_amdgcn_mfma_f32_32x32x16_bf16(ap, bv, O[nt], 0, 0, 0);
                    }
                    Ol = __builtin_amdgcn_mfma_f32_32x32x16_bf16(ap, ones, Ol, 0, 0, 0);
                }
            }
        }
    }

    // epilogue: divide by l, write Y[b,s,h*128+hd]
#pragma unroll
    for (int r = 0; r < 16; ++r) {
        int s = q0 + w * 32 + (r & 3) + 8 * (r >> 2) + 4 * hh;
        float inv = 1.0f / Ol[r];
        size_t base = ((size_t)(b * SS + s)) * DD + h * HDIM;
#pragma unroll
        for (int nt = 0; nt < 4; ++nt)
            Y[base + nt * 32 + l31] = f2bf(O[nt][r] * inv);
    }
}

// ---------------------------------------------------------------------------
extern "C" void kernel_launch(void* const* d_in, const int* in_sizes, int n_in,
                              void* d_out, int out_size, void* d_ws, size_t ws_size,
                              hipStream_t stream) {
    const float* x     = (const float*)d_in[0];
    const float* w_qkv = (const float*)d_in[1];
    const float* b_qkv = (const float*)d_in[2];
    const float* w_out = (const float*)d_in[3];
    const float* b_out = (const float*)d_in[4];
    float* out = (float*)d_out;

    ushort* ws  = (ushort*)d_ws;
    ushort* xb  = ws;                      // 8,388,608
    ushort* wtq = xb + 8388608;            // 12,582,912
    ushort* wto = wtq + 12582912;          // 4,194,304
    ushort* q   = wto + 4194304;           // 8,388,608
    ushort* k   = q + 8388608;
    ushort* v   = k + 8388608;             // [B,H,S,HD]
    ushort* vt  = v + 8388608;             // [B,H,HD,S]
    ushort* y   = vt + 8388608;

    cast_x_kernel<<<4096, 256, 0, stream>>>(x, xb);
    transpose_cast_kernel<<<dim3(192, 64), 256, 0, stream>>>(w_qkv, wtq, DD, 3 * DD);
    transpose_cast_kernel<<<dim3(64, 64), 256, 0, stream>>>(w_out, wto, DD, DD);
    gemm_qkv_kernel<<<dim3(48, 32), 256, 0, stream>>>(xb, wtq, b_qkv, q, k, v);
    transpose_v_kernel<<<dim3(64, 4, 32), 256, 0, stream>>>(v, vt);
    attn_mfma_kernel<<<dim3(16, 32), 256, 0, stream>>>(q, k, vt, y);
    gemm_out_kernel<<<dim3(16, 32), 256, 0, stream>>>(y, wto, b_out, out);
}